// Round 1
// baseline (466.161 us; speedup 1.0000x reference)
//
#include <hip/hip_runtime.h>
#include <stdint.h>

#define B_ 8
#define C_ 256
#define D_ 128
#define N_ 4096

typedef __bf16 bf16x8 __attribute__((ext_vector_type(8)));
typedef uint16_t u16x8 __attribute__((ext_vector_type(8)));
typedef uint16_t u16x4 __attribute__((ext_vector_type(4)));
typedef float f32x4 __attribute__((ext_vector_type(4)));
typedef uint32_t u32x2 __attribute__((ext_vector_type(2)));

__device__ inline uint16_t f2bf(float x) {
    union { float f; uint32_t u; } v; v.f = x;
    uint32_t u = v.u;
    return (uint16_t)((u + 0x7FFFu + ((u >> 16) & 1u)) >> 16);
}

__device__ inline float bf2f(uint16_t v) {
    union { uint32_t u; float f; } x; x.u = (uint32_t)v << 16; return x.f;
}

// pack two floats -> two bf16 in one u32 (low = lo, high = hi); compiler emits cvt_pk
__device__ inline uint32_t pkbf(float lo, float hi) {
    __bf16 l = (__bf16)lo, h = (__bf16)hi;
    uint16_t lu = __builtin_bit_cast(uint16_t, l);
    uint16_t hu = __builtin_bit_cast(uint16_t, h);
    return ((uint32_t)hu << 16) | (uint32_t)lu;
}

// device exp2 via v_exp_f32 (D = 2^S0)
__device__ inline float dexp2(float x) { return __builtin_amdgcn_exp2f(x); }

// ---------------- prep: fp32 weights -> bf16.
// W_theta absorbs 1/sqrt(D) * log2(e): S' = S*log2(e), so exp(S) == exp2(S').
__global__ __launch_bounds__(256) void prep_weights(
    const float* __restrict__ wt, const float* __restrict__ wp,
    const float* __restrict__ wg, const float* __restrict__ wo,
    uint16_t* __restrict__ bwt, uint16_t* __restrict__ bwp,
    uint16_t* __restrict__ bwg, uint16_t* __restrict__ bwo)
{
    int i = blockIdx.x * 256 + threadIdx.x;   // 0..32767
    const float scale = 0.127517431f;         // log2(e)/sqrt(128)
    bwt[i] = f2bf(wt[i] * scale);
    bwp[i] = f2bf(wp[i]);
    bwg[i] = f2bf(wg[i]);
    bwo[i] = f2bf(wo[i]);
}

// ---------------- projections: z=0 qp[B][N][D], z=1 kp[B][N][D], z=2 vpT[B][D][N]
__global__ __launch_bounds__(256) void proj_kernel(
    const float* __restrict__ q, const float* __restrict__ k, const float* __restrict__ v,
    const uint16_t* __restrict__ bwt, const uint16_t* __restrict__ bwp, const uint16_t* __restrict__ bwg,
    uint16_t* __restrict__ qp, uint16_t* __restrict__ kp, uint16_t* __restrict__ vpT)
{
    const int which = blockIdx.z;
    const float* src = (which == 0) ? q : ((which == 1) ? k : v);
    const uint16_t* w = (which == 0) ? bwt : ((which == 1) ? bwp : bwg);
    const int b   = blockIdx.y;
    const int n0  = blockIdx.x * 64;
    const int wav = threadIdx.x >> 6;
    const int lane = threadIdx.x & 63;
    const int col = lane & 15;
    const int quad = lane >> 4;
    const int n = n0 + wav * 16 + col;

    const float* srcb = src + (size_t)b * C_ * N_;

    f32x4 acc[8];
#pragma unroll
    for (int mf = 0; mf < 8; ++mf) acc[mf] = (f32x4){0.f, 0.f, 0.f, 0.f};

    for (int kc = 0; kc < 8; ++kc) {
        const int cbase = kc * 32 + quad * 8;
        u16x8 bb;
#pragma unroll
        for (int j = 0; j < 8; ++j)
            bb[j] = f2bf(srcb[(size_t)(cbase + j) * N_ + n]);
        bf16x8 bfrag = __builtin_bit_cast(bf16x8, bb);
#pragma unroll
        for (int mf = 0; mf < 8; ++mf) {
            bf16x8 afrag = *(const bf16x8*)(w + (size_t)(mf * 16 + col) * C_ + cbase);
            acc[mf] = __builtin_amdgcn_mfma_f32_16x16x32_bf16(afrag, bfrag, acc[mf], 0, 0, 0);
        }
    }

    if (which < 2) {
        uint16_t* dst = (which == 0) ? qp : kp;          // [B][N][D], d contiguous
        uint16_t* base = dst + ((size_t)b * N_ + n) * D_;
#pragma unroll
        for (int mf = 0; mf < 8; ++mf) {
            u16x4 pk;
#pragma unroll
            for (int r = 0; r < 4; ++r) pk[r] = f2bf(acc[mf][r]);
            *(u16x4*)(base + mf * 16 + quad * 4) = pk;
        }
    } else {
        uint16_t* base = vpT + (size_t)b * D_ * N_;       // [B][D][N], n contiguous
#pragma unroll
        for (int mf = 0; mf < 8; ++mf)
#pragma unroll
            for (int r = 0; r < 4; ++r) {
                int d = mf * 16 + quad * 4 + r;
                base[(size_t)d * N_ + n] = f2bf(acc[mf][r]);
            }
    }
}

// ---------------- pass 1 (v7): per-m denominators, then fold 1/denom into vpT.
// m-tile 32 -> 1024 blocks -> 4 blocks/CU (4 waves/SIMD), vs 2 before.
// inv_denom never goes to global: out[n,d] = sum_m exp2(S'[n,m]) * (invd[m]*vp[m,d]).
__global__ __launch_bounds__(256) void pass1_denom(
    const uint16_t* __restrict__ qp, const uint16_t* __restrict__ kp,
    uint16_t* __restrict__ vpT)
{
    const int b  = blockIdx.x & 7;              // XCD-local batch
    const int m0 = (blockIdx.x >> 3) * 32;
    const int wav = threadIdx.x >> 6;
    const int lane = threadIdx.x & 63;
    const int c = lane & 15;
    const int q = lane >> 4;

    const uint16_t* qpb = qp + (size_t)b * N_ * D_;
    const uint16_t* kpb = kp + (size_t)b * N_ * D_;

    bf16x8 bfr[2][4];
#pragma unroll
    for (int mf = 0; mf < 2; ++mf)
#pragma unroll
        for (int kc = 0; kc < 4; ++kc)
            bfr[mf][kc] = *(const bf16x8*)(kpb + (size_t)(m0 + mf * 16 + c) * D_ + kc * 32 + q * 8);

    float colsum[2] = {0.f, 0.f};

    for (int it = 0; it < 64; ++it) {
        const int nbase = it * 64 + wav * 16;
        bf16x8 afr[4];
#pragma unroll
        for (int kc = 0; kc < 4; ++kc)
            afr[kc] = *(const bf16x8*)(qpb + (size_t)(nbase + c) * D_ + kc * 32 + q * 8);
#pragma unroll
        for (int mf = 0; mf < 2; ++mf) {
            f32x4 acc = (f32x4){0.f, 0.f, 0.f, 0.f};
#pragma unroll
            for (int kc = 0; kc < 4; ++kc)
                acc = __builtin_amdgcn_mfma_f32_16x16x32_bf16(afr[kc], bfr[mf][kc], acc, 0, 0, 0);
#pragma unroll
            for (int r = 0; r < 4; ++r)
                colsum[mf] += dexp2(acc[r]);
        }
    }

    __shared__ float cs[4][32];
    __shared__ float sinv[32];
#pragma unroll
    for (int mf = 0; mf < 2; ++mf) {
        float s = colsum[mf];
        s += __shfl_down(s, 16, 64);
        s += __shfl_down(s, 32, 64);
        if (q == 0) cs[wav][mf * 16 + c] = s;
    }
    __syncthreads();
    if (threadIdx.x < 32) {
        float s = cs[0][threadIdx.x] + cs[1][threadIdx.x] + cs[2][threadIdx.x] + cs[3][threadIdx.x];
        sinv[threadIdx.x] = 1.0f / s;
    }
    __syncthreads();
    // scale vpT[b][d][m0..m0+32) by sinv[m]; blocks own disjoint 64B column slabs
    uint16_t* vtb = vpT + (size_t)b * D_ * N_;
#pragma unroll
    for (int j = 0; j < 16; ++j) {
        int e = threadIdx.x + j * 256;          // 0..4095
        int d = e >> 5, m = e & 31;
        size_t idx = (size_t)d * N_ + m0 + m;
        vtb[idx] = f2bf(bf2f(vtb[idx]) * sinv[m]);
    }
}

// ---------------- pass 2 (v7): barrier-free, LDS-staging-free attention.
// Each wave owns 64 q-rows (4x the old 16): K/V B-fragments amortized 4x.
// K/V frags load straight from L2 (per-XCD working set 3MB < 4MB L2).
// Swapped S = mfma(K, Q): lane holds P[m-contig][n=col] -> transpose to PV A-frag
// is 2 packed ds_write_b64 + 1 ds_read_b128 per 16-n group, wave-private, no syncs.
// vpT is pre-scaled by 1/denom (pass1), so P = exp2(S') raw. m-split x4 partials.
__global__ __launch_bounds__(256, 2) void pass2_attn(
    const uint16_t* __restrict__ qp, const uint16_t* __restrict__ kp,
    const uint16_t* __restrict__ vpT,
    uint16_t* __restrict__ ob0, uint16_t* __restrict__ ob1,
    uint16_t* __restrict__ ob2, uint16_t* __restrict__ ob3)
{
    const int b   = blockIdx.x & 7;             // XCD-local batch
    const int qtr = (blockIdx.x >> 3) & 3;      // m-quarter
    const int nsb = blockIdx.x >> 5;            // 0..15
    const int wav = threadIdx.x >> 6;
    const int lane = threadIdx.x & 63;
    const int c = lane & 15;
    const int q = lane >> 4;
    const int ntile = nsb * 256 + wav * 64;     // this wave's 64 q-rows

    const uint16_t* qpb = qp + (size_t)b * N_ * D_;
    const uint16_t* kpb = kp + (size_t)b * N_ * D_;
    const uint16_t* vtb = vpT + (size_t)b * D_ * N_;

    // wave-private P transpose buffer: [wav][nf][n-row 16][32 m + pad] u16,
    // row stride 72 u16 = 144 B (16B-aligned, phase-optimal banking on b128 reads)
    __shared__ __align__(16) uint16_t plds[4][4][16][72];   // 36,864 B

    bf16x8 qfr[4][4];
#pragma unroll
    for (int nf = 0; nf < 4; ++nf)
#pragma unroll
        for (int kc = 0; kc < 4; ++kc)
            qfr[nf][kc] = *(const bf16x8*)(qpb + (size_t)(ntile + nf * 16 + c) * D_ + kc * 32 + q * 8);

    f32x4 oacc[4][8];
#pragma unroll
    for (int nf = 0; nf < 4; ++nf)
#pragma unroll
        for (int df = 0; df < 8; ++df) oacc[nf][df] = (f32x4){0.f, 0.f, 0.f, 0.f};

    const int mstart = qtr * (N_ / 4);
    for (int ch = 0; ch < (N_ / 4) / 32; ++ch) {
        const int m0 = mstart + ch * 32;

        // K fragments for 32 m rows, direct from L2
        bf16x8 kf[2][4];
#pragma unroll
        for (int mf = 0; mf < 2; ++mf)
#pragma unroll
            for (int kc = 0; kc < 4; ++kc)
                kf[mf][kc] = *(const bf16x8*)(kpb + (size_t)(m0 + mf * 16 + c) * D_ + kc * 32 + q * 8);

        // S phase (swapped: A=K rows m, B=Q rows n) + exp2 + pack to plds
        __builtin_amdgcn_s_setprio(1);
#pragma unroll
        for (int nf = 0; nf < 4; ++nf) {
            f32x4 s0 = (f32x4){0.f, 0.f, 0.f, 0.f};
            f32x4 s1 = (f32x4){0.f, 0.f, 0.f, 0.f};
#pragma unroll
            for (int kc = 0; kc < 4; ++kc)
                s0 = __builtin_amdgcn_mfma_f32_16x16x32_bf16(kf[0][kc], qfr[nf][kc], s0, 0, 0, 0);
#pragma unroll
            for (int kc = 0; kc < 4; ++kc)
                s1 = __builtin_amdgcn_mfma_f32_16x16x32_bf16(kf[1][kc], qfr[nf][kc], s1, 0, 0, 0);
            // lane (q,c): s0[r] = S[m0+4q+r][ntile+nf*16+c]; s1[r] = +16 m
            uint32_t p00 = pkbf(dexp2(s0[0]), dexp2(s0[1]));
            uint32_t p01 = pkbf(dexp2(s0[2]), dexp2(s0[3]));
            uint32_t p10 = pkbf(dexp2(s1[0]), dexp2(s1[1]));
            uint32_t p11 = pkbf(dexp2(s1[2]), dexp2(s1[3]));
            uint16_t* row = &plds[wav][nf][c][0];
            *(u32x2*)(row + 4 * q)      = (u32x2){p00, p01};   // m-local 4q..4q+3
            *(u32x2*)(row + 16 + 4 * q) = (u32x2){p10, p11};   // m-local 16+4q..+3
        }
        __builtin_amdgcn_s_setprio(0);

        // V fragments (issued after kf consumed; latency covered by pack VALU + 2nd wave)
        bf16x8 vf[8];
#pragma unroll
        for (int df = 0; df < 8; ++df)
            vf[df] = *(const bf16x8*)(vtb + (size_t)(df * 16 + c) * N_ + m0 + q * 8);

        // P A-fragments: lane (q,c) reads n=c row, k = m-local 8q..8q+7
        bf16x8 pf[4];
#pragma unroll
        for (int nf = 0; nf < 4; ++nf)
            pf[nf] = *(const bf16x8*)(&plds[wav][nf][c][8 * q]);

        __builtin_amdgcn_s_setprio(1);
#pragma unroll
        for (int nf = 0; nf < 4; ++nf)
#pragma unroll
            for (int df = 0; df < 8; ++df)
                oacc[nf][df] = __builtin_amdgcn_mfma_f32_16x16x32_bf16(pf[nf], vf[df], oacc[nf][df], 0, 0, 0);
        __builtin_amdgcn_s_setprio(0);
    }

    uint16_t* obq = (qtr == 0) ? ob0 : (qtr == 1) ? ob1 : (qtr == 2) ? ob2 : ob3;
#pragma unroll
    for (int nf = 0; nf < 4; ++nf) {
        uint16_t* ob = obq + ((size_t)b * N_ + ntile + nf * 16) * D_;   // [B][N][D]
#pragma unroll
        for (int df = 0; df < 8; ++df)
#pragma unroll
            for (int r = 0; r < 4; ++r)
                ob[(size_t)(q * 4 + r) * D_ + df * 16 + c] = f2bf(oacc[nf][df][r]);
    }
}

// ---------------- pass 3: out[b][c][n] = v[b][c][n] + sum_d W_out[c][d]*(O0+O1+O2+O3)[n][d]
__global__ __launch_bounds__(256) void pass3_out(
    const uint16_t* __restrict__ ob0, const uint16_t* __restrict__ ob1,
    const uint16_t* __restrict__ ob2, const uint16_t* __restrict__ ob3,
    const uint16_t* __restrict__ bwo,
    const float* __restrict__ v, float* __restrict__ out)
{
    const int b  = blockIdx.y;
    const int n0 = blockIdx.x * 64;
    const int wav = threadIdx.x >> 6;
    const int lane = threadIdx.x & 63;
    const int col = lane & 15;
    const int quad = lane >> 4;
    const int n = n0 + wav * 16 + col;

    const float* vb = v + (size_t)b * C_ * N_;
    float* outb = out + (size_t)b * C_ * N_;
    const size_t off = ((size_t)b * N_ + n) * D_;

    bf16x8 f0[4], f1[4], f2[4], f3[4];
#pragma unroll
    for (int kc = 0; kc < 4; ++kc) {
        f0[kc] = *(const bf16x8*)(ob0 + off + kc * 32 + quad * 8);
        f1[kc] = *(const bf16x8*)(ob1 + off + kc * 32 + quad * 8);
        f2[kc] = *(const bf16x8*)(ob2 + off + kc * 32 + quad * 8);
        f3[kc] = *(const bf16x8*)(ob3 + off + kc * 32 + quad * 8);
    }

#pragma unroll
    for (int cf = 0; cf < 16; ++cf) {
        f32x4 acc = (f32x4){0.f, 0.f, 0.f, 0.f};
#pragma unroll
        for (int kc = 0; kc < 4; ++kc) {
            bf16x8 afr = *(const bf16x8*)(bwo + (size_t)(cf * 16 + col) * D_ + kc * 32 + quad * 8);
            acc = __builtin_amdgcn_mfma_f32_16x16x32_bf16(afr, f0[kc], acc, 0, 0, 0);
            acc = __builtin_amdgcn_mfma_f32_16x16x32_bf16(afr, f1[kc], acc, 0, 0, 0);
            acc = __builtin_amdgcn_mfma_f32_16x16x32_bf16(afr, f2[kc], acc, 0, 0, 0);
            acc = __builtin_amdgcn_mfma_f32_16x16x32_bf16(afr, f3[kc], acc, 0, 0, 0);
        }
#pragma unroll
        for (int r = 0; r < 4; ++r) {
            const int cc = cf * 16 + quad * 4 + r;
            const size_t idx = (size_t)cc * N_ + n;
            outb[idx] = vb[idx] + acc[r];
        }
    }
}

extern "C" void kernel_launch(void* const* d_in, const int* in_sizes, int n_in,
                              void* d_out, int out_size, void* d_ws, size_t ws_size,
                              hipStream_t stream) {
    const float* q  = (const float*)d_in[0];
    const float* k  = (const float*)d_in[1];
    const float* v  = (const float*)d_in[2];
    const float* wt = (const float*)d_in[3];
    const float* wp = (const float*)d_in[4];
    const float* wg = (const float*)d_in[5];
    const float* wo = (const float*)d_in[6];
    float* out = (float*)d_out;

    const size_t PROJ = (size_t)B_ * N_ * D_;   // 4,194,304 elems (8 MB bf16)
    uint16_t* qp  = (uint16_t*)d_ws;
    uint16_t* kp  = qp + PROJ;
    uint16_t* vpT = kp + PROJ;
    uint16_t* ob0 = vpT + PROJ;
    uint16_t* ob1 = ob0 + PROJ;
    uint16_t* ob2 = ob1 + PROJ;
    uint16_t* ob3 = ob2 + PROJ;
    uint16_t* bwt = ob3 + PROJ;
    uint16_t* bwp = bwt + (size_t)D_ * C_;
    uint16_t* bwg = bwp + (size_t)D_ * C_;
    uint16_t* bwo = bwg + (size_t)D_ * C_;
    // total ws use: 7*8MB + 4*64KB = 56.25 MB

    prep_weights<<<dim3(128), 256, 0, stream>>>(wt, wp, wg, wo, bwt, bwp, bwg, bwo);
    proj_kernel<<<dim3(N_ / 64, B_, 3), 256, 0, stream>>>(q, k, v, bwt, bwp, bwg, qp, kp, vpT);
    pass1_denom<<<dim3(1024), 256, 0, stream>>>(qp, kp, vpT);
    pass2_attn<<<dim3(512), 256, 0, stream>>>(qp, kp, vpT, ob0, ob1, ob2, ob3);
    pass3_out<<<dim3(N_ / 64, B_), 256, 0, stream>>>(ob0, ob1, ob2, ob3, bwo, v, out);
}

// Round 2
// 364.590 us; speedup vs baseline: 1.2786x; 1.2786x over previous
//
#include <hip/hip_runtime.h>
#include <stdint.h>

#define B_ 8
#define C_ 256
#define D_ 128
#define N_ 4096

typedef __bf16 bf16x8 __attribute__((ext_vector_type(8)));
typedef uint16_t u16x8 __attribute__((ext_vector_type(8)));
typedef uint16_t u16x4 __attribute__((ext_vector_type(4)));
typedef float f32x4 __attribute__((ext_vector_type(4)));
typedef uint32_t u32x2 __attribute__((ext_vector_type(2)));

__device__ inline uint16_t f2bf(float x) {
    union { float f; uint32_t u; } v; v.f = x;
    uint32_t u = v.u;
    return (uint16_t)((u + 0x7FFFu + ((u >> 16) & 1u)) >> 16);
}

__device__ inline float bf2f(uint16_t v) {
    union { uint32_t u; float f; } x; x.u = (uint32_t)v << 16; return x.f;
}

// pack two floats -> two bf16 in one u32 (low = lo, high = hi)
__device__ inline uint32_t pkbf(float lo, float hi) {
    __bf16 l = (__bf16)lo, h = (__bf16)hi;
    uint16_t lu = __builtin_bit_cast(uint16_t, l);
    uint16_t hu = __builtin_bit_cast(uint16_t, h);
    return ((uint32_t)hu << 16) | (uint32_t)lu;
}

__device__ inline float dexp2(float x) { return __builtin_amdgcn_exp2f(x); }

// ---------------- prep: fp32 weights -> bf16.
// W_theta absorbs 1/sqrt(D) * log2(e): S' = S*log2(e), so exp(S) == exp2(S').
__global__ __launch_bounds__(256) void prep_weights(
    const float* __restrict__ wt, const float* __restrict__ wp,
    const float* __restrict__ wg, const float* __restrict__ wo,
    uint16_t* __restrict__ bwt, uint16_t* __restrict__ bwp,
    uint16_t* __restrict__ bwg, uint16_t* __restrict__ bwo)
{
    int i = blockIdx.x * 256 + threadIdx.x;   // 0..32767
    const float scale = 0.127517431f;         // log2(e)/sqrt(128)
    bwt[i] = f2bf(wt[i] * scale);
    bwp[i] = f2bf(wp[i]);
    bwg[i] = f2bf(wg[i]);
    bwo[i] = f2bf(wo[i]);
}

// ---------------- projections: z=0 qp[B][N][D], z=1 kp[B][N][D], z=2 vpT[B][D][N]
__global__ __launch_bounds__(256) void proj_kernel(
    const float* __restrict__ q, const float* __restrict__ k, const float* __restrict__ v,
    const uint16_t* __restrict__ bwt, const uint16_t* __restrict__ bwp, const uint16_t* __restrict__ bwg,
    uint16_t* __restrict__ qp, uint16_t* __restrict__ kp, uint16_t* __restrict__ vpT)
{
    const int which = blockIdx.z;
    const float* src = (which == 0) ? q : ((which == 1) ? k : v);
    const uint16_t* w = (which == 0) ? bwt : ((which == 1) ? bwp : bwg);
    const int b   = blockIdx.y;
    const int n0  = blockIdx.x * 64;
    const int wav = threadIdx.x >> 6;
    const int lane = threadIdx.x & 63;
    const int col = lane & 15;
    const int quad = lane >> 4;
    const int n = n0 + wav * 16 + col;

    const float* srcb = src + (size_t)b * C_ * N_;

    f32x4 acc[8];
#pragma unroll
    for (int mf = 0; mf < 8; ++mf) acc[mf] = (f32x4){0.f, 0.f, 0.f, 0.f};

    for (int kc = 0; kc < 8; ++kc) {
        const int cbase = kc * 32 + quad * 8;
        u16x8 bb;
#pragma unroll
        for (int j = 0; j < 8; ++j)
            bb[j] = f2bf(srcb[(size_t)(cbase + j) * N_ + n]);
        bf16x8 bfrag = __builtin_bit_cast(bf16x8, bb);
#pragma unroll
        for (int mf = 0; mf < 8; ++mf) {
            bf16x8 afrag = *(const bf16x8*)(w + (size_t)(mf * 16 + col) * C_ + cbase);
            acc[mf] = __builtin_amdgcn_mfma_f32_16x16x32_bf16(afrag, bfrag, acc[mf], 0, 0, 0);
        }
    }

    if (which < 2) {
        uint16_t* dst = (which == 0) ? qp : kp;          // [B][N][D], d contiguous
        uint16_t* base = dst + ((size_t)b * N_ + n) * D_;
#pragma unroll
        for (int mf = 0; mf < 8; ++mf) {
            u16x4 pk;
#pragma unroll
            for (int r = 0; r < 4; ++r) pk[r] = f2bf(acc[mf][r]);
            *(u16x4*)(base + mf * 16 + quad * 4) = pk;
        }
    } else {
        uint16_t* base = vpT + (size_t)b * D_ * N_;       // [B][D][N], n contiguous
#pragma unroll
        for (int mf = 0; mf < 8; ++mf)
#pragma unroll
            for (int r = 0; r < 4; ++r) {
                int d = mf * 16 + quad * 4 + r;
                base[(size_t)d * N_ + n] = f2bf(acc[mf][r]);
            }
    }
}

// ---------------- pass 1 (v8): m-tile 128, n-split x2 -> partial colsums.
// qp L2 traffic: 512 blocks x 512KB = 256MB (was 1GB at m-tile 32).
// 32 MFMA per 4 afr loads. Partials to part[ns][b][m] (fp32), no atomics.
__global__ __launch_bounds__(256) void pass1_denom(
    const uint16_t* __restrict__ qp, const uint16_t* __restrict__ kp,
    float* __restrict__ part)
{
    const int b  = blockIdx.x & 7;              // XCD-local batch
    const int mt = (blockIdx.x >> 3) & 31;
    const int ns = blockIdx.x >> 8;             // n-half 0..1
    const int m0 = mt * 128;
    const int wav = threadIdx.x >> 6;
    const int lane = threadIdx.x & 63;
    const int c = lane & 15;
    const int q = lane >> 4;

    const uint16_t* qpb = qp + (size_t)b * N_ * D_;
    const uint16_t* kpb = kp + (size_t)b * N_ * D_;

    bf16x8 bfr[8][4];
#pragma unroll
    for (int mf = 0; mf < 8; ++mf)
#pragma unroll
        for (int kc = 0; kc < 4; ++kc)
            bfr[mf][kc] = *(const bf16x8*)(kpb + (size_t)(m0 + mf * 16 + c) * D_ + kc * 32 + q * 8);

    float colsum[8];
#pragma unroll
    for (int mf = 0; mf < 8; ++mf) colsum[mf] = 0.f;

    for (int it = 0; it < 32; ++it) {
        const int nbase = ns * 2048 + it * 64 + wav * 16;
        bf16x8 afr[4];
#pragma unroll
        for (int kc = 0; kc < 4; ++kc)
            afr[kc] = *(const bf16x8*)(qpb + (size_t)(nbase + c) * D_ + kc * 32 + q * 8);
#pragma unroll
        for (int mf = 0; mf < 8; ++mf) {
            f32x4 acc = (f32x4){0.f, 0.f, 0.f, 0.f};
#pragma unroll
            for (int kc = 0; kc < 4; ++kc)
                acc = __builtin_amdgcn_mfma_f32_16x16x32_bf16(afr[kc], bfr[mf][kc], acc, 0, 0, 0);
#pragma unroll
            for (int r = 0; r < 4; ++r)
                colsum[mf] += dexp2(acc[r]);
        }
    }

    __shared__ float cs[4][128];
#pragma unroll
    for (int mf = 0; mf < 8; ++mf) {
        float s = colsum[mf];
        s += __shfl_down(s, 16, 64);
        s += __shfl_down(s, 32, 64);
        if (q == 0) cs[wav][mf * 16 + c] = s;
    }
    __syncthreads();
    if (threadIdx.x < 128) {
        float s = cs[0][threadIdx.x] + cs[1][threadIdx.x] + cs[2][threadIdx.x] + cs[3][threadIdx.x];
        part[((size_t)ns * 8 + b) * N_ + m0 + threadIdx.x] = s;
    }
}

// ---------------- scale_vpt: vpT[b][d][m] *= 1/(part0[b][m]+part1[b][m])
__global__ __launch_bounds__(256) void scale_vpt(
    const float* __restrict__ part, uint16_t* __restrict__ vpT)
{
    const size_t base = ((size_t)blockIdx.x * 256 + threadIdx.x) * 8;  // u16 index in [B][D][N]
    const int b = (int)(base >> 19);            // D_*N_ = 2^19
    const int m = (int)(base & (N_ - 1));
    const float* p0 = part + (size_t)b * N_ + m;
    const float* p1 = part + (size_t)(8 + b) * N_ + m;
    u16x8 v = *(const u16x8*)(vpT + base);
    u16x8 r;
#pragma unroll
    for (int j = 0; j < 8; ++j) {
        float inv = __builtin_amdgcn_rcpf(p0[j] + p1[j]);
        r[j] = f2bf(bf2f(v[j]) * inv);
    }
    *(u16x8*)(vpT + base) = r;
}

// ---------------- pass 2 (v8): v7 structure + LDS-staged K/V shared by 4 waves.
// Round-1 counters: MfmaUtil 20.7%, L2 frag traffic 128KB/CU/chunk = 2300cy vs
// 640cy MFMA -> L2-BW bound. Staging K+V via global_load_lds (16B, linear dest,
// swizzled SOURCE per m104/m173) cuts that 4x; LDS reads ~24KB/wave/chunk.
// K granule (m,j) stored at j^(m&7); V granule (d,j) at j^((d>>1)&3) ->
// fragment ds_read_b128s are 2-way (free). One __syncthreads per 32-m chunk,
// double-buffered prefetch issued at top of loop (drain ~1500cy later: cheap).
__global__ __launch_bounds__(256, 2) void pass2_attn(
    const uint16_t* __restrict__ qp, const uint16_t* __restrict__ kp,
    const uint16_t* __restrict__ vpT,
    uint16_t* __restrict__ ob0, uint16_t* __restrict__ ob1,
    uint16_t* __restrict__ ob2, uint16_t* __restrict__ ob3)
{
    const int b   = blockIdx.x & 7;             // XCD-local batch
    const int qtr = (blockIdx.x >> 3) & 3;      // m-quarter
    const int nsb = blockIdx.x >> 5;            // 0..15
    const int wav = threadIdx.x >> 6;
    const int lane = threadIdx.x & 63;
    const int c = lane & 15;
    const int q = lane >> 4;
    const int ntile = nsb * 256 + wav * 64;     // this wave's 64 q-rows

    const uint16_t* qpb = qp + (size_t)b * N_ * D_;
    const uint16_t* kpb = kp + (size_t)b * N_ * D_;
    const uint16_t* vtb = vpT + (size_t)b * D_ * N_;

    // K tile [0,4096) u16: 32 m x 128 d, granule-swizzled. V tile [4096,8192):
    // 128 d x 32 m. Double-buffered: 32 KB.
    __shared__ __align__(16) uint16_t stage[2][8192];
    // wave-private P transpose buffer, row stride 72 u16 = 144 B
    __shared__ __align__(16) uint16_t plds[4][4][16][72];   // 36,864 B

#define STAGE(bufidx, m0_)                                                          \
    {                                                                               \
        uint16_t* lb = &stage[bufidx][0];                                           \
        _Pragma("unroll")                                                           \
        for (int j = 0; j < 4; ++j) {                                               \
            const int fid = wav * 4 + j;                                            \
            const uint16_t* g;                                                      \
            uint16_t* ld;                                                           \
            if (fid < 8) {                                                          \
                const int P = fid * 64 + lane;                                      \
                const int mm = P >> 4, js = P & 15;                                 \
                const int jj = js ^ (mm & 7);                                       \
                g = kpb + (size_t)((m0_) + mm) * D_ + jj * 8;                       \
                ld = lb + fid * 512;                                                \
            } else {                                                                \
                const int P = (fid - 8) * 64 + lane;                                \
                const int dd = P >> 2, js = P & 3;                                  \
                const int jj = js ^ ((dd >> 1) & 3);                                \
                g = vtb + (size_t)dd * N_ + (m0_) + jj * 8;                         \
                ld = lb + 4096 + (fid - 8) * 512;                                   \
            }                                                                       \
            __builtin_amdgcn_global_load_lds(                                       \
                (const __attribute__((address_space(1))) unsigned int*)g,           \
                (__attribute__((address_space(3))) unsigned int*)ld,                \
                16, 0, 0);                                                          \
        }                                                                           \
    }

    bf16x8 qfr[4][4];
#pragma unroll
    for (int nf = 0; nf < 4; ++nf)
#pragma unroll
        for (int kc = 0; kc < 4; ++kc)
            qfr[nf][kc] = *(const bf16x8*)(qpb + (size_t)(ntile + nf * 16 + c) * D_ + kc * 32 + q * 8);

    f32x4 oacc[4][8];
#pragma unroll
    for (int nf = 0; nf < 4; ++nf)
#pragma unroll
        for (int df = 0; df < 8; ++df) oacc[nf][df] = (f32x4){0.f, 0.f, 0.f, 0.f};

    const int mstart = qtr * (N_ / 4);
    STAGE(0, mstart);
    __syncthreads();

    for (int ch = 0; ch < 32; ++ch) {
        const int m0 = mstart + ch * 32;
        const int cur = ch & 1;
        STAGE(cur ^ 1, mstart + ((ch + 1) & 31) * 32);   // prefetch (last iter: dead)

        const uint16_t* sb = &stage[cur][0];

        // K fragments from LDS (swizzled): lane (q,c), m = mf*16+c, j = kc*4+q
        bf16x8 kf[2][4];
#pragma unroll
        for (int mf = 0; mf < 2; ++mf)
#pragma unroll
            for (int kc = 0; kc < 4; ++kc) {
                const int js = (kc * 4 + q) ^ (c & 7);   // m&7 == c&7
                kf[mf][kc] = *(const bf16x8*)(sb + (mf * 16 + c) * 128 + js * 8);
            }

        // S phase (swapped: A=K rows m, B=Q rows n) + exp2 + pack to plds
        __builtin_amdgcn_s_setprio(1);
#pragma unroll
        for (int nf = 0; nf < 4; ++nf) {
            f32x4 s0 = (f32x4){0.f, 0.f, 0.f, 0.f};
            f32x4 s1 = (f32x4){0.f, 0.f, 0.f, 0.f};
#pragma unroll
            for (int kc = 0; kc < 4; ++kc)
                s0 = __builtin_amdgcn_mfma_f32_16x16x32_bf16(kf[0][kc], qfr[nf][kc], s0, 0, 0, 0);
#pragma unroll
            for (int kc = 0; kc < 4; ++kc)
                s1 = __builtin_amdgcn_mfma_f32_16x16x32_bf16(kf[1][kc], qfr[nf][kc], s1, 0, 0, 0);
            // lane (q,c): s0[r] = S[m0+4q+r][ntile+nf*16+c]; s1[r] = +16 m
            uint32_t p00 = pkbf(dexp2(s0[0]), dexp2(s0[1]));
            uint32_t p01 = pkbf(dexp2(s0[2]), dexp2(s0[3]));
            uint32_t p10 = pkbf(dexp2(s1[0]), dexp2(s1[1]));
            uint32_t p11 = pkbf(dexp2(s1[2]), dexp2(s1[3]));
            uint16_t* row = &plds[wav][nf][c][0];
            *(u32x2*)(row + 4 * q)      = (u32x2){p00, p01};   // m-local 4q..4q+3
            *(u32x2*)(row + 16 + 4 * q) = (u32x2){p10, p11};   // m-local 16+4q..+3
        }
        __builtin_amdgcn_s_setprio(0);

        // V fragments from LDS (swizzled): lane (q,c), d = df*16+c, j = q
        const int vjs = q ^ ((c >> 1) & 3);    // (d>>1)&3 == (c>>1)&3
        bf16x8 vf[8];
#pragma unroll
        for (int df = 0; df < 8; ++df)
            vf[df] = *(const bf16x8*)(sb + 4096 + (df * 16 + c) * 32 + vjs * 8);

        // P A-fragments: lane (q,c) reads n=c row, k = m-local 8q..8q+7
        bf16x8 pf[4];
#pragma unroll
        for (int nf = 0; nf < 4; ++nf)
            pf[nf] = *(const bf16x8*)(&plds[wav][nf][c][8 * q]);

        __builtin_amdgcn_s_setprio(1);
#pragma unroll
        for (int nf = 0; nf < 4; ++nf)
#pragma unroll
            for (int df = 0; df < 8; ++df)
                oacc[nf][df] = __builtin_amdgcn_mfma_f32_16x16x32_bf16(pf[nf], vf[df], oacc[nf][df], 0, 0, 0);
        __builtin_amdgcn_s_setprio(0);

        __syncthreads();   // all waves done reading cur + own prefetch DMA drained
    }
#undef STAGE

    uint16_t* obq = (qtr == 0) ? ob0 : (qtr == 1) ? ob1 : (qtr == 2) ? ob2 : ob3;
#pragma unroll
    for (int nf = 0; nf < 4; ++nf) {
        uint16_t* ob = obq + ((size_t)b * N_ + ntile + nf * 16) * D_;   // [B][N][D]
#pragma unroll
        for (int df = 0; df < 8; ++df)
#pragma unroll
            for (int r = 0; r < 4; ++r)
                ob[(size_t)(q * 4 + r) * D_ + df * 16 + c] = f2bf(oacc[nf][df][r]);
    }
}

// ---------------- pass 3: out[b][c][n] = v[b][c][n] + sum_d W_out[c][d]*(O0+O1+O2+O3)[n][d]
__global__ __launch_bounds__(256) void pass3_out(
    const uint16_t* __restrict__ ob0, const uint16_t* __restrict__ ob1,
    const uint16_t* __restrict__ ob2, const uint16_t* __restrict__ ob3,
    const uint16_t* __restrict__ bwo,
    const float* __restrict__ v, float* __restrict__ out)
{
    const int b  = blockIdx.y;
    const int n0 = blockIdx.x * 64;
    const int wav = threadIdx.x >> 6;
    const int lane = threadIdx.x & 63;
    const int col = lane & 15;
    const int quad = lane >> 4;
    const int n = n0 + wav * 16 + col;

    const float* vb = v + (size_t)b * C_ * N_;
    float* outb = out + (size_t)b * C_ * N_;
    const size_t off = ((size_t)b * N_ + n) * D_;

    bf16x8 f0[4], f1[4], f2[4], f3[4];
#pragma unroll
    for (int kc = 0; kc < 4; ++kc) {
        f0[kc] = *(const bf16x8*)(ob0 + off + kc * 32 + quad * 8);
        f1[kc] = *(const bf16x8*)(ob1 + off + kc * 32 + quad * 8);
        f2[kc] = *(const bf16x8*)(ob2 + off + kc * 32 + quad * 8);
        f3[kc] = *(const bf16x8*)(ob3 + off + kc * 32 + quad * 8);
    }

#pragma unroll
    for (int cf = 0; cf < 16; ++cf) {
        f32x4 acc = (f32x4){0.f, 0.f, 0.f, 0.f};
#pragma unroll
        for (int kc = 0; kc < 4; ++kc) {
            bf16x8 afr = *(const bf16x8*)(bwo + (size_t)(cf * 16 + col) * D_ + kc * 32 + quad * 8);
            acc = __builtin_amdgcn_mfma_f32_16x16x32_bf16(afr, f0[kc], acc, 0, 0, 0);
            acc = __builtin_amdgcn_mfma_f32_16x16x32_bf16(afr, f1[kc], acc, 0, 0, 0);
            acc = __builtin_amdgcn_mfma_f32_16x16x32_bf16(afr, f2[kc], acc, 0, 0, 0);
            acc = __builtin_amdgcn_mfma_f32_16x16x32_bf16(afr, f3[kc], acc, 0, 0, 0);
        }
#pragma unroll
        for (int r = 0; r < 4; ++r) {
            const int cc = cf * 16 + quad * 4 + r;
            const size_t idx = (size_t)cc * N_ + n;
            outb[idx] = vb[idx] + acc[r];
        }
    }
}

extern "C" void kernel_launch(void* const* d_in, const int* in_sizes, int n_in,
                              void* d_out, int out_size, void* d_ws, size_t ws_size,
                              hipStream_t stream) {
    const float* q  = (const float*)d_in[0];
    const float* k  = (const float*)d_in[1];
    const float* v  = (const float*)d_in[2];
    const float* wt = (const float*)d_in[3];
    const float* wp = (const float*)d_in[4];
    const float* wg = (const float*)d_in[5];
    const float* wo = (const float*)d_in[6];
    float* out = (float*)d_out;

    const size_t PROJ = (size_t)B_ * N_ * D_;   // 4,194,304 elems (8 MB bf16)
    uint16_t* qp  = (uint16_t*)d_ws;
    uint16_t* kp  = qp + PROJ;
    uint16_t* vpT = kp + PROJ;
    uint16_t* ob0 = vpT + PROJ;
    uint16_t* ob1 = ob0 + PROJ;
    uint16_t* ob2 = ob1 + PROJ;
    uint16_t* ob3 = ob2 + PROJ;
    uint16_t* bwt = ob3 + PROJ;
    uint16_t* bwp = bwt + (size_t)D_ * C_;
    uint16_t* bwg = bwp + (size_t)D_ * C_;
    uint16_t* bwo = bwg + (size_t)D_ * C_;
    // part[2][8][4096] fp32 (256 KB) aliases ob0: consumed by scale_vpt BEFORE
    // pass2 writes ob0. total ws use: 7*8MB + 4*64KB = 56.25 MB
    float* part = (float*)ob0;

    prep_weights<<<dim3(128), 256, 0, stream>>>(wt, wp, wg, wo, bwt, bwp, bwg, bwo);
    proj_kernel<<<dim3(N_ / 64, B_, 3), 256, 0, stream>>>(q, k, v, bwt, bwp, bwg, qp, kp, vpT);
    pass1_denom<<<dim3(512), 256, 0, stream>>>(qp, kp, part);
    scale_vpt<<<dim3(2048), 256, 0, stream>>>(part, vpT);
    pass2_attn<<<dim3(512), 256, 0, stream>>>(qp, kp, vpT, ob0, ob1, ob2, ob3);
    pass3_out<<<dim3(N_ / 64, B_), 256, 0, stream>>>(ob0, ob1, ob2, ob3, bwo, v, out);
}